// Round 15
// baseline (547.341 us; speedup 1.0000x reference)
//
#include <hip/hip_runtime.h>

#define DD 128
typedef unsigned int u32;
typedef __attribute__((ext_vector_type(8))) short bf16x8;
typedef __attribute__((ext_vector_type(4))) float f32x4;

__device__ __forceinline__ float lrelu(float v, float s) { return v >= 0.f ? v : s * v; }
__device__ __forceinline__ ushort f2bf(float f) {
  union { float f; u32 u; } v; v.f = f;
  u32 u = v.u;
  return (ushort)((u + 0x7FFFu + ((u >> 16) & 1u)) >> 16);  // RNE
}
__device__ __forceinline__ float bf2f(ushort s) { return __uint_as_float(((u32)s) << 16); }

union frag_cvt { uint4 u; bf16x8 h; };

// ---------------- prep: W^T -> bf16 MFMA A-fragment layout ----------------
__global__ __launch_bounds__(256) void k_prep_w(const float* __restrict__ W,
                                                short* __restrict__ WA)
{
  int t = blockIdx.x * 256 + threadIdx.x;  // 6144
  int lane = t & 63, ks = (t >> 6) & 3, cf = (t >> 8) & 7, r = t >> 11;
  int c = cf * 16 + (lane & 15);
  int kb = ks * 32 + (lane >> 4) * 8;
  const float* Wr = W + (size_t)r * DD * DD;
  ushort o[8];
#pragma unroll
  for (int j = 0; j < 8; j++) o[j] = f2bf(Wr[(size_t)(kb + j) * DD + c]);
  uint4 st;
  st.x = (u32)o[0] | ((u32)o[1] << 16);
  st.y = (u32)o[2] | ((u32)o[3] << 16);
  st.z = (u32)o[4] | ((u32)o[5] << 16);
  st.w = (u32)o[6] | ((u32)o[7] << 16);
  *(uint4*)(WA + (size_t)t * 8) = st;
}

// ---------------- prep: bi_w/si_w -> bf16 A-frags ----------------
__global__ __launch_bounds__(256) void k_prep_cw(const float* __restrict__ bw,
                                                 const float* __restrict__ sw,
                                                 short* __restrict__ WB)
{
  int t = blockIdx.x * 256 + threadIdx.x;  // 4096
  int lane = t & 63, ks = (t >> 6) & 3, cf = (t >> 8) & 7, m = t >> 11;
  const float* src = m ? sw : bw;
  int c = cf * 16 + (lane & 15);
  int k = ks * 32 + (lane >> 4) * 8;
  const float* pr = src + (size_t)c * DD + k;
  uint4 st;
  st.x = (u32)f2bf(pr[0]) | ((u32)f2bf(pr[1]) << 16);
  st.y = (u32)f2bf(pr[2]) | ((u32)f2bf(pr[3]) << 16);
  st.z = (u32)f2bf(pr[4]) | ((u32)f2bf(pr[5]) << 16);
  st.w = (u32)f2bf(pr[6]) | ((u32)f2bf(pr[7]) << 16);
  *(uint4*)(WB + (size_t)t * 8) = st;
}

// ---------------- prep: wl = W @ attn_l, wr = W @ attn_r ----------------
__global__ void k_prep_av(const float* __restrict__ W, const float* __restrict__ al,
                          const float* __restrict__ ar, float* __restrict__ wl,
                          float* __restrict__ wr)
{
  int t = blockIdx.x * 192 + threadIdx.x;  // 384
  if (t >= 384) return;
  int r = t >> 7, k = t & 127;
  const float* Wrow = W + (size_t)r * DD * DD + (size_t)k * DD;
  const float* alr = al + r * DD;
  const float* arr = ar + r * DD;
  float pl = 0.f, pr = 0.f;
  for (int c = 0; c < DD; c++) { float w = Wrow[c]; pl = fmaf(w, alr[c], pl); pr = fmaf(w, arr[c], pr); }
  wl[t] = pl; wr[t] = pr;
}

// ---------------- prep: x -> bf16 rows + el; er packed into bex[].y ----------------
__global__ __launch_bounds__(256) void k_prep_xrow(
    const float* __restrict__ x, const float* __restrict__ wl, const float* __restrict__ wr,
    u32* __restrict__ xrow, float* __restrict__ el, int2* __restrict__ bex, int N)
{
  const int wid = (int)(((long long)blockIdx.x * 256 + threadIdx.x) >> 6);
  const int lane = threadIdx.x & 63;
  if (wid >= N) return;
  float2 xv = *(const float2*)(x + (size_t)wid * DD + lane * 2);
  xrow[(size_t)wid * 64 + lane] = (u32)f2bf(xv.x) | ((u32)f2bf(xv.y) << 16);
  float d[6];
#pragma unroll
  for (int r = 0; r < 3; r++) {
    float2 wlv = *(const float2*)(wl + r * DD + lane * 2);
    float2 wrv = *(const float2*)(wr + r * DD + lane * 2);
    d[r]     = xv.x * wlv.x + xv.y * wlv.y;
    d[r + 3] = xv.x * wrv.x + xv.y * wrv.y;
  }
#pragma unroll
  for (int o = 32; o; o >>= 1) {
#pragma unroll
    for (int k = 0; k < 6; k++) d[k] += __shfl_xor(d[k], o);
  }
  if (lane == 0) {
#pragma unroll
    for (int r = 0; r < 3; r++) {
      el[(size_t)r * N + wid] = d[r];
      bex[(size_t)r * N + wid].y = __float_as_int(d[r + 3]);  // er
    }
  }
}

// ---------------- CSR build: histogram of dst + rank store (grid.y = r) ----------------
__global__ void k_hist3(const int* __restrict__ dst, int* __restrict__ cnt,
                        int* __restrict__ rank, int N, int E) {
  int i = blockIdx.x * 256 + threadIdx.x;
  int r = blockIdx.y;
  if (i < E) {
    size_t ei = (size_t)r * E + i;
    rank[ei] = atomicAdd(cnt + (size_t)r * N + dst[ei], 1);
  }
}

// ---------------- hierarchical scan: bex[0..M].x ----------------
__global__ __launch_bounds__(256) void k_scan_bsum(const int* __restrict__ cnt,
                                                   int* __restrict__ bsum, int M)
{
  __shared__ int red[256];
  const int t = threadIdx.x;
  const int g0 = blockIdx.x * 2048 + t * 8;
  int s = 0;
#pragma unroll
  for (int j = 0; j < 8; j++) { int i = g0 + j; if (i < M) s += cnt[i]; }
  red[t] = s;
  __syncthreads();
  for (int o = 128; o; o >>= 1) {
    if (t < o) red[t] += red[t + o];
    __syncthreads();
  }
  if (t == 0) bsum[blockIdx.x] = red[0];
}

__global__ __launch_bounds__(256) void k_scan_btop(const int* __restrict__ bsum,
                                                   int* __restrict__ bpre, int NB)
{
  __shared__ int sums[256];
  const int t = threadIdx.x;
  int v = (t < NB) ? bsum[t] : 0;
  sums[t] = v;
  __syncthreads();
  for (int o = 1; o < 256; o <<= 1) {
    int u = (t >= o) ? sums[t - o] : 0;
    __syncthreads();
    sums[t] += u;
    __syncthreads();
  }
  if (t < NB) bpre[t] = sums[t] - v;
}

__global__ __launch_bounds__(256) void k_scan_base(const int* __restrict__ cnt,
    const int* __restrict__ bpre, int2* __restrict__ bex, int M)
{
  __shared__ int sums[256];
  const int t = threadIdx.x;
  const int g0 = blockIdx.x * 2048 + t * 8;
  int c[8];
  int ts = 0;
#pragma unroll
  for (int j = 0; j < 8; j++) { int i = g0 + j; c[j] = (i < M) ? cnt[i] : 0; ts += c[j]; }
  sums[t] = ts;
  __syncthreads();
  for (int o = 1; o < 256; o <<= 1) {
    int u = (t >= o) ? sums[t - o] : 0;
    __syncthreads();
    sums[t] += u;
    __syncthreads();
  }
  int run = bpre[blockIdx.x] + sums[t] - ts;
#pragma unroll
  for (int j = 0; j < 8; j++) {
    int i = g0 + j;
    if (i <= M) bex[i].x = run;
    run += c[j];
  }
}

// ---------------- scatter: meta[base+rank] = (src, bf16(e)|bf16(ew)); no atomics ----------------
__global__ void k_scatter3(const int* __restrict__ src, const int* __restrict__ dst,
    const float* __restrict__ ew, const float* __restrict__ el,
    const int* __restrict__ rank, const int2* __restrict__ bex,
    int2* __restrict__ meta, int N, int E)
{
  int i = blockIdx.x * 256 + threadIdx.x;
  if (i >= E) return;
  int r = blockIdx.y;
  size_t ei = (size_t)r * E + i;
  int d = dst[ei], s = src[ei];
  int2 be = bex[(size_t)r * N + d];
  int pos = be.x + rank[ei];
  float e = lrelu(el[(size_t)r * N + s] + __int_as_float(be.y), 0.2f);
  meta[pos] = make_int2(s, (int)((u32)f2bf(e) | ((u32)f2bf(ew[ei]) << 16)));
}

// ---------------- per-node softmax(no-max)+x-aggregation, all 3 relations ----------------
// lane owns 4 channels (ql*4..+3); halves process even/odd edges; uint2 gathers.
__global__ __launch_bounds__(256) void k_node_agg3(
    const int2* __restrict__ bex, const int2* __restrict__ meta,
    const u32* __restrict__ xrow, u32* __restrict__ aggx, int N, int Np)
{
  const int wid = (int)(((long long)blockIdx.x * 256 + threadIdx.x) >> 6);
  const int lane = threadIdx.x & 63;
  if (wid >= N) return;
  const char* xb = (const char*)xrow;
  const int ql = lane & 31, half = lane >> 5;
  const u32 qb = (u32)ql << 3;

  int b0[3], dg[3];
#pragma unroll
  for (int r = 0; r < 3; r++) {
    int v0 = bex[r * N + wid].x;
    int v1 = bex[r * N + wid + 1].x;
    b0[r] = v0; dg[r] = v1 - v0;
  }

  float A0[3] = {0,0,0}, A1[3] = {0,0,0}, A2[3] = {0,0,0}, A3[3] = {0,0,0}, SS[3];

  if (dg[0] <= 64 && dg[1] <= 64 && dg[2] <= 64) {
    int sv[3]; float av[3], cwv[3];
#pragma unroll
    for (int r = 0; r < 3; r++) {
      int s = 0; float a = 0.f, c = 0.f;
      if (lane < dg[r]) {
        int2 mm = meta[b0[r] + lane];
        s = mm.x;
        float e = bf2f((ushort)((u32)mm.y & 0xFFFFu));
        float w = bf2f((ushort)((u32)mm.y >> 16));
        a = __expf(fminf(e, 60.f));
        c = a * w;
      }
      sv[r] = s; av[r] = a; cwv[r] = c;
    }
#pragma unroll
    for (int r = 0; r < 3; r++) {
      float s = av[r];
#pragma unroll
      for (int o = 32; o; o >>= 1) s += __shfl_xor(s, o);
      SS[r] = s;
    }
    // chunk 0 peel across relations: up to 12 8B loads in flight
    float cc[3][4]; u32 so[3][4];
#pragma unroll
    for (int r = 0; r < 3; r++)
#pragma unroll
      for (int q = 0; q < 4; q++) {
        int j = q * 2 + half;
        cc[r][q] = __shfl(cwv[r], j);
        so[r][q] = ((u32)__shfl(sv[r], j) << 8) | qb;
      }
    uint2 uu[3][4];
#pragma unroll
    for (int r = 0; r < 3; r++)
#pragma unroll
      for (int q = 0; q < 4; q++) uu[r][q] = *(const uint2*)(xb + so[r][q]);
#pragma unroll
    for (int r = 0; r < 3; r++)
#pragma unroll
      for (int q = 0; q < 4; q++) {
        A0[r] = fmaf(cc[r][q], __uint_as_float(uu[r][q].x << 16), A0[r]);
        A1[r] = fmaf(cc[r][q], __uint_as_float(uu[r][q].x & 0xFFFF0000u), A1[r]);
        A2[r] = fmaf(cc[r][q], __uint_as_float(uu[r][q].y << 16), A2[r]);
        A3[r] = fmaf(cc[r][q], __uint_as_float(uu[r][q].y & 0xFFFF0000u), A3[r]);
      }
    // remaining chunks
#pragma unroll
    for (int r = 0; r < 3; r++) {
      for (int c8 = 8; c8 < dg[r]; c8 += 8) {
        float c2[4]; u32 o2[4];
#pragma unroll
        for (int q = 0; q < 4; q++) {
          int j = c8 + q * 2 + half;
          c2[q] = __shfl(cwv[r], j);
          o2[q] = ((u32)__shfl(sv[r], j) << 8) | qb;
        }
        uint2 u2[4];
#pragma unroll
        for (int q = 0; q < 4; q++) u2[q] = *(const uint2*)(xb + o2[q]);
#pragma unroll
        for (int q = 0; q < 4; q++) {
          A0[r] = fmaf(c2[q], __uint_as_float(u2[q].x << 16), A0[r]);
          A1[r] = fmaf(c2[q], __uint_as_float(u2[q].x & 0xFFFF0000u), A1[r]);
          A2[r] = fmaf(c2[q], __uint_as_float(u2[q].y << 16), A2[r]);
          A3[r] = fmaf(c2[q], __uint_as_float(u2[q].y & 0xFFFF0000u), A3[r]);
        }
      }
    }
  } else {
    // generic fallback (deg > 64 somewhere)
#pragma unroll
    for (int r = 0; r < 3; r++) {
      float sp = 0.f;
      for (int c0 = 0; c0 < dg[r]; c0 += 64) {
        int kk = min(64, dg[r] - c0);
        int s = 0; float a = 0.f, c = 0.f;
        if (lane < kk) {
          int2 mm = meta[b0[r] + c0 + lane];
          s = mm.x;
          float e = bf2f((ushort)((u32)mm.y & 0xFFFFu));
          float w = bf2f((ushort)((u32)mm.y >> 16));
          a = __expf(fminf(e, 60.f));
          c = a * w;
        }
        sp += a;
        for (int c8 = 0; c8 < kk; c8 += 8) {
          float c2[4]; u32 o2[4];
#pragma unroll
          for (int q = 0; q < 4; q++) {
            int j = c8 + q * 2 + half;
            c2[q] = __shfl(c, j);
            o2[q] = ((u32)__shfl(s, j) << 8) | qb;
          }
          uint2 u2[4];
#pragma unroll
          for (int q = 0; q < 4; q++) u2[q] = *(const uint2*)(xb + o2[q]);
#pragma unroll
          for (int q = 0; q < 4; q++) {
            A0[r] = fmaf(c2[q], __uint_as_float(u2[q].x << 16), A0[r]);
            A1[r] = fmaf(c2[q], __uint_as_float(u2[q].x & 0xFFFF0000u), A1[r]);
            A2[r] = fmaf(c2[q], __uint_as_float(u2[q].y << 16), A2[r]);
            A3[r] = fmaf(c2[q], __uint_as_float(u2[q].y & 0xFFFF0000u), A3[r]);
          }
        }
      }
#pragma unroll
      for (int o = 32; o; o >>= 1) sp += __shfl_xor(sp, o);
      SS[r] = sp;
    }
  }

  // cross-half reduce, then write (half 0 lanes cover the full 256B row)
#pragma unroll
  for (int r = 0; r < 3; r++) {
    A0[r] += __shfl_xor(A0[r], 32);
    A1[r] += __shfl_xor(A1[r], 32);
    A2[r] += __shfl_xor(A2[r], 32);
    A3[r] += __shfl_xor(A3[r], 32);
  }
  if (half == 0) {
#pragma unroll
    for (int r = 0; r < 3; r++) {
      const float inv = (dg[r] > 0) ? 1.f / SS[r] : 0.f;
      uint2 o;
      o.x = (u32)f2bf(A0[r] * inv) | ((u32)f2bf(A1[r] * inv) << 16);
      o.y = (u32)f2bf(A2[r] * inv) | ((u32)f2bf(A3[r] * inv) << 16);
      *(uint2*)(aggx + ((size_t)r * Np + wid) * 64 + ql * 2) = o;
    }
  }
}

// ---------------- fused tail: feats MFMA + combine MFMA + LN, barrier-free tile loop ----------------
// 512 thr = 8 waves x 16 nodes. LDS: WA 96KB (staged ONCE) + 34KB per-wave bufs.
// WB fragments read directly from global (L2-broadcast, coalesced 1KB/frag).
__global__ __launch_bounds__(512) void k_tail2(
    const u32* __restrict__ aggx, const short* __restrict__ WA,
    const short* __restrict__ WB, const float* __restrict__ gb,
    const float* __restrict__ x,
    const float* __restrict__ bi_b, const float* __restrict__ si_b,
    const float* __restrict__ res_w, const float* __restrict__ ln_g,
    const float* __restrict__ ln_b, float* __restrict__ out,
    int N, int Np, int ntiles)
{
  extern __shared__ u32 lds[];
  u32* lwa = lds;                 // 24576 u32 (96 KB): all 3 relations, staged once
  const int tid = threadIdx.x;
  const int lane = tid & 63;
  const int w = tid >> 6;
  u32* wbuf = lds + 24576 + w * 1088;   // per-wave scratch (frag relayout / out relayout)
  float* obuf = (float*)wbuf;           // 16 x 66 f32 view

  for (int i = tid; i < 6144; i += 512)
    *(uint4*)&lwa[i * 4] = *(const uint4*)(WA + (size_t)i * 8);
  __syncthreads();  // the only barrier

  const int nl = lane & 15, fh = lane >> 4;
  const float sigw = 1.f / (1.f + __expf(-res_w[0]));
  const float gA = ln_g[lane], bA = ln_b[lane];
  const float gB = ln_g[64 + lane], bB = ln_b[64 + lane];

  for (int tile = blockIdx.x; tile < ntiles; tile += gridDim.x) {
    const int tb = tile * 128 + w * 16;
    const int node = tb + nl;

    f32x4 sa[8], qa[8];
#pragma unroll
    for (int cf = 0; cf < 8; cf++) { sa[cf] = (f32x4){0,0,0,0}; qa[cf] = (f32x4){0,0,0,0}; }

    for (int r = 0; r < 3; r++) {
      // stage this wave's 16 aggx rows (lane-linear 256B loads) into per-wave LDS
#pragma unroll
      for (int rr = 0; rr < 16; rr++)
        wbuf[rr * 68 + lane] = aggx[((size_t)r * Np + tb + rr) * 64 + lane];
      bf16x8 bf[4];
#pragma unroll
      for (int ks = 0; ks < 4; ks++) {
        frag_cvt cv;
        cv.u = *(const uint4*)&wbuf[nl * 68 + ks * 16 + fh * 4];
        bf[ks] = cv.h;
      }
      f32x4 acc[8];
#pragma unroll
      for (int cf = 0; cf < 8; cf++) acc[cf] = (f32x4){0,0,0,0};
#pragma unroll
      for (int ks = 0; ks < 4; ks++) {
#pragma unroll
        for (int cf = 0; cf < 8; cf++) {
          frag_cvt av;
          av.u = *(const uint4*)&lwa[(((r * 8 + cf) * 4 + ks) * 64 + lane) * 4];
          acc[cf] = __builtin_amdgcn_mfma_f32_16x16x32_bf16(av.h, bf[ks], acc[cf], 0, 0, 0);
        }
      }
#pragma unroll
      for (int cf = 0; cf < 8; cf++) {
        float4 g4 = *(const float4*)(gb + r * DD + cf * 16 + fh * 4);
        const float* gp = (const float*)&g4;
#pragma unroll
        for (int j = 0; j < 4; j++) {
          float f = acc[cf][j] + gp[j];
          sa[cf][j] += f;
          qa[cf][j] += f * f;
        }
      }
    }

    // relayout s -> sf frags (per-wave LDS)
    bf16x8 sf[4], df[4];
#pragma unroll
    for (int cf = 0; cf < 8; cf++) {
      int wb = cf * 8 + fh * 2;
      wbuf[nl * 68 + wb]     = (u32)f2bf(sa[cf][0]) | ((u32)f2bf(sa[cf][1]) << 16);
      wbuf[nl * 68 + wb + 1] = (u32)f2bf(sa[cf][2]) | ((u32)f2bf(sa[cf][3]) << 16);
    }
#pragma unroll
    for (int ks = 0; ks < 4; ks++) {
      frag_cvt cv;
      cv.u = *(const uint4*)&wbuf[nl * 68 + ks * 16 + fh * 4];
      sf[ks] = cv.h;
    }
    // relayout dfm -> df frags
#pragma unroll
    for (int cf = 0; cf < 8; cf++) {
      int wb = cf * 8 + fh * 2;
      float d0 = 0.5f * (sa[cf][0] * sa[cf][0] - qa[cf][0]);
      float d1 = 0.5f * (sa[cf][1] * sa[cf][1] - qa[cf][1]);
      float d2 = 0.5f * (sa[cf][2] * sa[cf][2] - qa[cf][2]);
      float d3 = 0.5f * (sa[cf][3] * sa[cf][3] - qa[cf][3]);
      wbuf[nl * 68 + wb]     = (u32)f2bf(d0) | ((u32)f2bf(d1) << 16);
      wbuf[nl * 68 + wb + 1] = (u32)f2bf(d2) | ((u32)f2bf(d3) << 16);
    }
#pragma unroll
    for (int ks = 0; ks < 4; ks++) {
      frag_cvt cv;
      cv.u = *(const uint4*)&wbuf[nl * 68 + ks * 16 + fh * 4];
      df[ks] = cv.h;
    }

    // combine MFMA: WB frags straight from global (L2-resident, coalesced)
    f32x4 accB[8], accS[8];
#pragma unroll
    for (int cf = 0; cf < 8; cf++) {
      accB[cf] = (f32x4){0,0,0,0};
      accS[cf] = (f32x4){0,0,0,0};
    }
#pragma unroll
    for (int ks = 0; ks < 4; ks++) {
#pragma unroll
      for (int cf = 0; cf < 8; cf++) {
        frag_cvt ab, as;
        ab.u = *(const uint4*)(WB + ((((size_t)0 * 8 + cf) * 4 + ks) * 64 + lane) * 8);
        as.u = *(const uint4*)(WB + ((((size_t)1 * 8 + cf) * 4 + ks) * 64 + lane) * 8);
        accB[cf] = __builtin_amdgcn_mfma_f32_16x16x32_bf16(ab.h, df[ks], accB[cf], 0, 0, 0);
        accS[cf] = __builtin_amdgcn_mfma_f32_16x16x32_bf16(as.h, sf[ks], accS[cf], 0, 0, 0);
      }
    }

    // epilogue: vals in registers, LN stats, two-pass coalesced out via obuf
    float4 vals[8];
    float sv = 0.f, sq = 0.f;
#pragma unroll
    for (int cf = 0; cf < 8; cf++) {
      int c0 = cf * 16 + fh * 4;
      float4 bb4 = *(const float4*)(bi_b + c0);
      float4 sb4 = *(const float4*)(si_b + c0);
      float4 xv = make_float4(0.f, 0.f, 0.f, 0.f);
      if (node < N) xv = *(const float4*)(x + (size_t)node * DD + c0);
      const float* bbp = (const float*)&bb4;
      const float* sbp = (const float*)&sb4;
      const float* xvp = (const float*)&xv;
      float* vp = (float*)&vals[cf];
#pragma unroll
      for (int j = 0; j < 4; j++) {
        float val = lrelu(accB[cf][j] + bbp[j], 0.01f)
                  + lrelu(accS[cf][j] + sbp[j], 0.01f)
                  + xvp[j] * sigw;
        vp[j] = val;
        sv += val; sq += val * val;
      }
    }
    sv += __shfl_xor(sv, 16); sq += __shfl_xor(sq, 16);
    sv += __shfl_xor(sv, 32); sq += __shfl_xor(sq, 32);
    const float mu = sv * (1.f / DD);
    const float var = sq * (1.f / DD) - mu * mu;
    const float rs = rsqrtf(var + 1e-5f);

#pragma unroll
    for (int half = 0; half < 2; half++) {
      const float g = half ? gB : gA;
      const float b = half ? bB : bA;
#pragma unroll
      for (int cf = 0; cf < 4; cf++)
        *(float4*)&obuf[nl * 66 + cf * 16 + fh * 4] = vals[half * 4 + cf];
#pragma unroll
      for (int rr = 0; rr < 16; rr++) {
        int n2 = tb + rr;
        if (n2 >= N) continue;
        float mur = __shfl(mu, rr);
        float rsr = __shfl(rs, rr);
        float v = obuf[rr * 66 + lane];
        out[(size_t)n2 * DD + half * 64 + lane] = (v - mur) * rsr * g + b;
      }
    }
  }
}

extern "C" void kernel_launch(void* const* d_in, const int* in_sizes, int n_in,
                              void* d_out, int out_size, void* d_ws, size_t ws_size,
                              hipStream_t stream)
{
  const float* x    = (const float*)d_in[0];
  const int*   esrc = (const int*)d_in[1];
  const int*   edst = (const int*)d_in[2];
  const float* ew   = (const float*)d_in[3];
  const float* W    = (const float*)d_in[4];
  const float* al   = (const float*)d_in[5];
  const float* ar   = (const float*)d_in[6];
  const float* gb   = (const float*)d_in[7];
  const float* bi_w = (const float*)d_in[8];
  const float* bi_b = (const float*)d_in[9];
  const float* si_w = (const float*)d_in[10];
  const float* si_b = (const float*)d_in[11];
  const float* res_w= (const float*)d_in[12];
  const float* ln_g = (const float*)d_in[13];
  const float* ln_b = (const float*)d_in[14];

  const int N = in_sizes[0] / DD;
  const int R = 3;
  const int E = in_sizes[1] / R;
  const int Np = ((N + 127) / 128) * 128;
  const int M = R * N;
  const int NB = (M + 2047) / 2048;
  const int ntiles = Np / 128;

  auto al256 = [](size_t v) { return (v + 255) & ~(size_t)255; };
  char* p = (char*)d_ws;
  u32*   xrow  = (u32*)p;  p += al256((size_t)Np * 64 * 4);
  // region C: rank [hist..scatter]  then  aggx [node_agg..tail2]
  int*   rank  = (int*)p;
  u32*   aggx  = (u32*)p;
  p += al256((size_t)R * Np * 64 * 4);
  int2*  meta  = (int2*)p;  p += al256((size_t)R * E * 8);
  float* el    = (float*)p; p += al256((size_t)M * 4);
  int2*  bex   = (int2*)p;  p += al256(((size_t)M + 1) * 8);
  int*   cnt   = (int*)p;   p += al256((size_t)M * 4);
  short* WA    = (short*)p; p += al256((size_t)R * 8 * 4 * 64 * 8 * 2);
  short* WB    = (short*)p; p += al256((size_t)2 * 8 * 4 * 64 * 8 * 2);
  float* wl    = (float*)p; p += al256((size_t)R * DD * 4);
  float* wr    = (float*)p; p += al256((size_t)R * DD * 4);
  int*   bsum  = (int*)p;   p += 1024;
  int*   bpre  = (int*)p;   p += 1024;

  const int egrid = (E + 255) / 256;
  const int DYN_LDS = 133120;  // 96 KB WA + 34 KB per-wave bufs

  hipFuncSetAttribute((const void*)k_tail2,
                      hipFuncAttributeMaxDynamicSharedMemorySize, DYN_LDS);

  k_prep_w<<<24, 256, 0, stream>>>(W, WA);
  k_prep_cw<<<16, 256, 0, stream>>>(bi_w, si_w, WB);
  k_prep_av<<<2, 192, 0, stream>>>(W, al, ar, wl, wr);
  k_prep_xrow<<<(N + 3) / 4, 256, 0, stream>>>(x, wl, wr, xrow, el, bex, N);

  hipMemsetAsync(cnt, 0, (size_t)M * 4, stream);
  k_hist3<<<dim3(egrid, 3), 256, 0, stream>>>(edst, cnt, rank, N, E);
  k_scan_bsum<<<NB, 256, 0, stream>>>(cnt, bsum, M);
  k_scan_btop<<<1, 256, 0, stream>>>(bsum, bpre, NB);
  k_scan_base<<<NB, 256, 0, stream>>>(cnt, bpre, bex, M);
  k_scatter3<<<dim3(egrid, 3), 256, 0, stream>>>(esrc, edst, ew, el, rank, bex,
                                                 meta, N, E);
  k_node_agg3<<<(N + 3) / 4, 256, 0, stream>>>(bex, meta, xrow, aggx, N, Np);
  k_tail2<<<256, 512, DYN_LDS, stream>>>(aggx, WA, WB, gb, x, bi_b, si_b,
                                         res_w, ln_g, ln_b, (float*)d_out,
                                         N, Np, ntiles);
}

// Round 16
// 317.935 us; speedup vs baseline: 1.7216x; 1.7216x over previous
//
#include <hip/hip_runtime.h>

#define DD 128
typedef unsigned int u32;
typedef __attribute__((ext_vector_type(8))) short bf16x8;
typedef __attribute__((ext_vector_type(4))) float f32x4;

__device__ __forceinline__ float lrelu(float v, float s) { return v >= 0.f ? v : s * v; }
__device__ __forceinline__ ushort f2bf(float f) {
  union { float f; u32 u; } v; v.f = f;
  u32 u = v.u;
  return (ushort)((u + 0x7FFFu + ((u >> 16) & 1u)) >> 16);  // RNE
}
__device__ __forceinline__ float bf2f(ushort s) { return __uint_as_float(((u32)s) << 16); }

union frag_cvt { uint4 u; bf16x8 h; };

// ---------------- prep: W^T -> bf16 MFMA A-fragment layout ----------------
__global__ __launch_bounds__(256) void k_prep_w(const float* __restrict__ W,
                                                short* __restrict__ WA)
{
  int t = blockIdx.x * 256 + threadIdx.x;  // 6144
  int lane = t & 63, ks = (t >> 6) & 3, cf = (t >> 8) & 7, r = t >> 11;
  int c = cf * 16 + (lane & 15);
  int kb = ks * 32 + (lane >> 4) * 8;
  const float* Wr = W + (size_t)r * DD * DD;
  ushort o[8];
#pragma unroll
  for (int j = 0; j < 8; j++) o[j] = f2bf(Wr[(size_t)(kb + j) * DD + c]);
  uint4 st;
  st.x = (u32)o[0] | ((u32)o[1] << 16);
  st.y = (u32)o[2] | ((u32)o[3] << 16);
  st.z = (u32)o[4] | ((u32)o[5] << 16);
  st.w = (u32)o[6] | ((u32)o[7] << 16);
  *(uint4*)(WA + (size_t)t * 8) = st;
}

// ---------------- prep: bi_w/si_w -> bf16 A-frags ----------------
__global__ __launch_bounds__(256) void k_prep_cw(const float* __restrict__ bw,
                                                 const float* __restrict__ sw,
                                                 short* __restrict__ WB)
{
  int t = blockIdx.x * 256 + threadIdx.x;  // 4096
  int lane = t & 63, ks = (t >> 6) & 3, cf = (t >> 8) & 7, m = t >> 11;
  const float* src = m ? sw : bw;
  int c = cf * 16 + (lane & 15);
  int k = ks * 32 + (lane >> 4) * 8;
  const float* pr = src + (size_t)c * DD + k;
  uint4 st;
  st.x = (u32)f2bf(pr[0]) | ((u32)f2bf(pr[1]) << 16);
  st.y = (u32)f2bf(pr[2]) | ((u32)f2bf(pr[3]) << 16);
  st.z = (u32)f2bf(pr[4]) | ((u32)f2bf(pr[5]) << 16);
  st.w = (u32)f2bf(pr[6]) | ((u32)f2bf(pr[7]) << 16);
  *(uint4*)(WB + (size_t)t * 8) = st;
}

// ---------------- prep: wl = W @ attn_l, wr = W @ attn_r ----------------
__global__ void k_prep_av(const float* __restrict__ W, const float* __restrict__ al,
                          const float* __restrict__ ar, float* __restrict__ wl,
                          float* __restrict__ wr)
{
  int t = blockIdx.x * 192 + threadIdx.x;  // 384
  if (t >= 384) return;
  int r = t >> 7, k = t & 127;
  const float* Wrow = W + (size_t)r * DD * DD + (size_t)k * DD;
  const float* alr = al + r * DD;
  const float* arr = ar + r * DD;
  float pl = 0.f, pr = 0.f;
  for (int c = 0; c < DD; c++) { float w = Wrow[c]; pl = fmaf(w, alr[c], pl); pr = fmaf(w, arr[c], pr); }
  wl[t] = pl; wr[t] = pr;
}

// ---------------- prep: x -> bf16 rows + el; er packed into bex[].y ----------------
__global__ __launch_bounds__(256) void k_prep_xrow(
    const float* __restrict__ x, const float* __restrict__ wl, const float* __restrict__ wr,
    u32* __restrict__ xrow, float* __restrict__ el, int2* __restrict__ bex, int N)
{
  const int wid = (int)(((long long)blockIdx.x * 256 + threadIdx.x) >> 6);
  const int lane = threadIdx.x & 63;
  if (wid >= N) return;
  float2 xv = *(const float2*)(x + (size_t)wid * DD + lane * 2);
  xrow[(size_t)wid * 64 + lane] = (u32)f2bf(xv.x) | ((u32)f2bf(xv.y) << 16);
  float d[6];
#pragma unroll
  for (int r = 0; r < 3; r++) {
    float2 wlv = *(const float2*)(wl + r * DD + lane * 2);
    float2 wrv = *(const float2*)(wr + r * DD + lane * 2);
    d[r]     = xv.x * wlv.x + xv.y * wlv.y;
    d[r + 3] = xv.x * wrv.x + xv.y * wrv.y;
  }
#pragma unroll
  for (int o = 32; o; o >>= 1) {
#pragma unroll
    for (int k = 0; k < 6; k++) d[k] += __shfl_xor(d[k], o);
  }
  if (lane == 0) {
#pragma unroll
    for (int r = 0; r < 3; r++) {
      el[(size_t)r * N + wid] = d[r];
      bex[(size_t)r * N + wid].y = __float_as_int(d[r + 3]);  // er
    }
  }
}

// ---------------- CSR build: histogram of dst + rank store (grid.y = r) ----------------
__global__ void k_hist3(const int* __restrict__ dst, int* __restrict__ cnt,
                        int* __restrict__ rank, int N, int E) {
  int i = blockIdx.x * 256 + threadIdx.x;
  int r = blockIdx.y;
  if (i < E) {
    size_t ei = (size_t)r * E + i;
    rank[ei] = atomicAdd(cnt + (size_t)r * N + dst[ei], 1);
  }
}

// ---------------- hierarchical scan: bex[0..M].x ----------------
__global__ __launch_bounds__(256) void k_scan_bsum(const int* __restrict__ cnt,
                                                   int* __restrict__ bsum, int M)
{
  __shared__ int red[256];
  const int t = threadIdx.x;
  const int g0 = blockIdx.x * 2048 + t * 8;
  int s = 0;
#pragma unroll
  for (int j = 0; j < 8; j++) { int i = g0 + j; if (i < M) s += cnt[i]; }
  red[t] = s;
  __syncthreads();
  for (int o = 128; o; o >>= 1) {
    if (t < o) red[t] += red[t + o];
    __syncthreads();
  }
  if (t == 0) bsum[blockIdx.x] = red[0];
}

__global__ __launch_bounds__(256) void k_scan_btop(const int* __restrict__ bsum,
                                                   int* __restrict__ bpre, int NB)
{
  __shared__ int sums[256];
  const int t = threadIdx.x;
  int v = (t < NB) ? bsum[t] : 0;
  sums[t] = v;
  __syncthreads();
  for (int o = 1; o < 256; o <<= 1) {
    int u = (t >= o) ? sums[t - o] : 0;
    __syncthreads();
    sums[t] += u;
    __syncthreads();
  }
  if (t < NB) bpre[t] = sums[t] - v;
}

__global__ __launch_bounds__(256) void k_scan_base(const int* __restrict__ cnt,
    const int* __restrict__ bpre, int2* __restrict__ bex, int M)
{
  __shared__ int sums[256];
  const int t = threadIdx.x;
  const int g0 = blockIdx.x * 2048 + t * 8;
  int c[8];
  int ts = 0;
#pragma unroll
  for (int j = 0; j < 8; j++) { int i = g0 + j; c[j] = (i < M) ? cnt[i] : 0; ts += c[j]; }
  sums[t] = ts;
  __syncthreads();
  for (int o = 1; o < 256; o <<= 1) {
    int u = (t >= o) ? sums[t - o] : 0;
    __syncthreads();
    sums[t] += u;
    __syncthreads();
  }
  int run = bpre[blockIdx.x] + sums[t] - ts;
#pragma unroll
  for (int j = 0; j < 8; j++) {
    int i = g0 + j;
    if (i <= M) bex[i].x = run;
    run += c[j];
  }
}

// ---------------- scatter: meta[base+rank] = (src, bf16(e)|bf16(ew)); no atomics ----------------
__global__ void k_scatter3(const int* __restrict__ src, const int* __restrict__ dst,
    const float* __restrict__ ew, const float* __restrict__ el,
    const int* __restrict__ rank, const int2* __restrict__ bex,
    int2* __restrict__ meta, int N, int E)
{
  int i = blockIdx.x * 256 + threadIdx.x;
  if (i >= E) return;
  int r = blockIdx.y;
  size_t ei = (size_t)r * E + i;
  int d = dst[ei], s = src[ei];
  int2 be = bex[(size_t)r * N + d];
  int pos = be.x + rank[ei];
  float e = lrelu(el[(size_t)r * N + s] + __int_as_float(be.y), 0.2f);
  meta[pos] = make_int2(s, (int)((u32)f2bf(e) | ((u32)f2bf(ew[ei]) << 16)));
}

// ---------------- per-node softmax(no-max)+x-aggregation, all 3 relations ----------------
// lane owns 4 channels (ql*4..+3); halves process even/odd edges; uint2 gathers.
__global__ __launch_bounds__(256) void k_node_agg3(
    const int2* __restrict__ bex, const int2* __restrict__ meta,
    const u32* __restrict__ xrow, u32* __restrict__ aggx, int N, int Np)
{
  const int wid = (int)(((long long)blockIdx.x * 256 + threadIdx.x) >> 6);
  const int lane = threadIdx.x & 63;
  if (wid >= N) return;
  const char* xb = (const char*)xrow;
  const int ql = lane & 31, half = lane >> 5;
  const u32 qb = (u32)ql << 3;

  int b0[3], dg[3];
#pragma unroll
  for (int r = 0; r < 3; r++) {
    int v0 = bex[r * N + wid].x;
    int v1 = bex[r * N + wid + 1].x;
    b0[r] = v0; dg[r] = v1 - v0;
  }

  float A0[3] = {0,0,0}, A1[3] = {0,0,0}, A2[3] = {0,0,0}, A3[3] = {0,0,0}, SS[3];

  if (dg[0] <= 64 && dg[1] <= 64 && dg[2] <= 64) {
    int sv[3]; float av[3], cwv[3];
#pragma unroll
    for (int r = 0; r < 3; r++) {
      int s = 0; float a = 0.f, c = 0.f;
      if (lane < dg[r]) {
        int2 mm = meta[b0[r] + lane];
        s = mm.x;
        float e = bf2f((ushort)((u32)mm.y & 0xFFFFu));
        float w = bf2f((ushort)((u32)mm.y >> 16));
        a = __expf(fminf(e, 60.f));
        c = a * w;
      }
      sv[r] = s; av[r] = a; cwv[r] = c;
    }
#pragma unroll
    for (int r = 0; r < 3; r++) {
      float s = av[r];
#pragma unroll
      for (int o = 32; o; o >>= 1) s += __shfl_xor(s, o);
      SS[r] = s;
    }
    // chunk 0 peel across relations: up to 12 8B loads in flight
    float cc[3][4]; u32 so[3][4];
#pragma unroll
    for (int r = 0; r < 3; r++)
#pragma unroll
      for (int q = 0; q < 4; q++) {
        int j = q * 2 + half;
        cc[r][q] = __shfl(cwv[r], j);
        so[r][q] = ((u32)__shfl(sv[r], j) << 8) | qb;
      }
    uint2 uu[3][4];
#pragma unroll
    for (int r = 0; r < 3; r++)
#pragma unroll
      for (int q = 0; q < 4; q++) uu[r][q] = *(const uint2*)(xb + so[r][q]);
#pragma unroll
    for (int r = 0; r < 3; r++)
#pragma unroll
      for (int q = 0; q < 4; q++) {
        A0[r] = fmaf(cc[r][q], __uint_as_float(uu[r][q].x << 16), A0[r]);
        A1[r] = fmaf(cc[r][q], __uint_as_float(uu[r][q].x & 0xFFFF0000u), A1[r]);
        A2[r] = fmaf(cc[r][q], __uint_as_float(uu[r][q].y << 16), A2[r]);
        A3[r] = fmaf(cc[r][q], __uint_as_float(uu[r][q].y & 0xFFFF0000u), A3[r]);
      }
    // remaining chunks
#pragma unroll
    for (int r = 0; r < 3; r++) {
      for (int c8 = 8; c8 < dg[r]; c8 += 8) {
        float c2[4]; u32 o2[4];
#pragma unroll
        for (int q = 0; q < 4; q++) {
          int j = c8 + q * 2 + half;
          c2[q] = __shfl(cwv[r], j);
          o2[q] = ((u32)__shfl(sv[r], j) << 8) | qb;
        }
        uint2 u2[4];
#pragma unroll
        for (int q = 0; q < 4; q++) u2[q] = *(const uint2*)(xb + o2[q]);
#pragma unroll
        for (int q = 0; q < 4; q++) {
          A0[r] = fmaf(c2[q], __uint_as_float(u2[q].x << 16), A0[r]);
          A1[r] = fmaf(c2[q], __uint_as_float(u2[q].x & 0xFFFF0000u), A1[r]);
          A2[r] = fmaf(c2[q], __uint_as_float(u2[q].y << 16), A2[r]);
          A3[r] = fmaf(c2[q], __uint_as_float(u2[q].y & 0xFFFF0000u), A3[r]);
        }
      }
    }
  } else {
    // generic fallback (deg > 64 somewhere)
#pragma unroll
    for (int r = 0; r < 3; r++) {
      float sp = 0.f;
      for (int c0 = 0; c0 < dg[r]; c0 += 64) {
        int kk = min(64, dg[r] - c0);
        int s = 0; float a = 0.f, c = 0.f;
        if (lane < kk) {
          int2 mm = meta[b0[r] + c0 + lane];
          s = mm.x;
          float e = bf2f((ushort)((u32)mm.y & 0xFFFFu));
          float w = bf2f((ushort)((u32)mm.y >> 16));
          a = __expf(fminf(e, 60.f));
          c = a * w;
        }
        sp += a;
        for (int c8 = 0; c8 < kk; c8 += 8) {
          float c2[4]; u32 o2[4];
#pragma unroll
          for (int q = 0; q < 4; q++) {
            int j = c8 + q * 2 + half;
            c2[q] = __shfl(c, j);
            o2[q] = ((u32)__shfl(s, j) << 8) | qb;
          }
          uint2 u2[4];
#pragma unroll
          for (int q = 0; q < 4; q++) u2[q] = *(const uint2*)(xb + o2[q]);
#pragma unroll
          for (int q = 0; q < 4; q++) {
            A0[r] = fmaf(c2[q], __uint_as_float(u2[q].x << 16), A0[r]);
            A1[r] = fmaf(c2[q], __uint_as_float(u2[q].x & 0xFFFF0000u), A1[r]);
            A2[r] = fmaf(c2[q], __uint_as_float(u2[q].y << 16), A2[r]);
            A3[r] = fmaf(c2[q], __uint_as_float(u2[q].y & 0xFFFF0000u), A3[r]);
          }
        }
      }
#pragma unroll
      for (int o = 32; o; o >>= 1) sp += __shfl_xor(sp, o);
      SS[r] = sp;
    }
  }

  // cross-half reduce, then write (half 0 lanes cover the full 256B row)
#pragma unroll
  for (int r = 0; r < 3; r++) {
    A0[r] += __shfl_xor(A0[r], 32);
    A1[r] += __shfl_xor(A1[r], 32);
    A2[r] += __shfl_xor(A2[r], 32);
    A3[r] += __shfl_xor(A3[r], 32);
  }
  if (half == 0) {
#pragma unroll
    for (int r = 0; r < 3; r++) {
      const float inv = (dg[r] > 0) ? 1.f / SS[r] : 0.f;
      uint2 o;
      o.x = (u32)f2bf(A0[r] * inv) | ((u32)f2bf(A1[r] * inv) << 16);
      o.y = (u32)f2bf(A2[r] * inv) | ((u32)f2bf(A3[r] * inv) << 16);
      *(uint2*)(aggx + ((size_t)r * Np + wid) * 64 + ql * 2) = o;
    }
  }
}

// ---------------- fused tail: feats MFMA + combine MFMA + LN, one kernel ----------------
// 512 thr = 8 waves x 16 nodes. LDS: WB 64KB (once) + WA_r 32KB (per tile,r) + 34KB bufs.
__global__ __launch_bounds__(512) void k_tail2(
    const u32* __restrict__ aggx, const short* __restrict__ WA,
    const short* __restrict__ WB, const float* __restrict__ gb,
    const float* __restrict__ x,
    const float* __restrict__ bi_b, const float* __restrict__ si_b,
    const float* __restrict__ res_w, const float* __restrict__ ln_g,
    const float* __restrict__ ln_b, float* __restrict__ out,
    int N, int Np, int ntiles)
{
  extern __shared__ u32 lds[];
  u32* lwb = lds;                 // 16384 u32 (64 KB), staged once
  u32* lwa = lds + 16384;         // 8192 u32 (32 KB), restaged per (tile, r)
  const int tid = threadIdx.x;
  const int lane = tid & 63;
  const int w = tid >> 6;
  u32* wbuf = lds + 24576 + w * 1088;   // per-wave scratch (frag relayout / out relayout)
  float* obuf = (float*)wbuf;           // 16 x 66 f32 view

  for (int i = tid; i < 4096; i += 512)
    *(uint4*)&lwb[i * 4] = *(const uint4*)(WB + (size_t)i * 8);

  const int nl = lane & 15, fh = lane >> 4;
  const float sigw = 1.f / (1.f + __expf(-res_w[0]));
  const float gA = ln_g[lane], bA = ln_b[lane];
  const float gB = ln_g[64 + lane], bB = ln_b[64 + lane];

  for (int tile = blockIdx.x; tile < ntiles; tile += gridDim.x) {
    const int tb = tile * 128 + w * 16;
    const int node = tb + nl;

    f32x4 sa[8], qa[8];
#pragma unroll
    for (int cf = 0; cf < 8; cf++) { sa[cf] = (f32x4){0,0,0,0}; qa[cf] = (f32x4){0,0,0,0}; }

    for (int r = 0; r < 3; r++) {
      __syncthreads();  // protect lwa (and first-iter lwb) from previous use
      for (int i = tid; i < 2048; i += 512)
        *(uint4*)&lwa[i * 4] = *(const uint4*)(WA + ((size_t)r * 2048 + i) * 8);
      __syncthreads();

      // stage this wave's 16 aggx rows (lane-linear 256B loads)
#pragma unroll
      for (int rr = 0; rr < 16; rr++)
        wbuf[rr * 68 + lane] = aggx[((size_t)r * Np + tb + rr) * 64 + lane];
      bf16x8 bf[4];
#pragma unroll
      for (int ks = 0; ks < 4; ks++) {
        frag_cvt cv;
        cv.u = *(const uint4*)&wbuf[nl * 68 + ks * 16 + fh * 4];
        bf[ks] = cv.h;
      }
      f32x4 acc[8];
#pragma unroll
      for (int cf = 0; cf < 8; cf++) acc[cf] = (f32x4){0,0,0,0};
#pragma unroll
      for (int ks = 0; ks < 4; ks++) {
#pragma unroll
        for (int cf = 0; cf < 8; cf++) {
          frag_cvt av;
          av.u = *(const uint4*)&lwa[(((cf) * 4 + ks) * 64 + lane) * 4];
          acc[cf] = __builtin_amdgcn_mfma_f32_16x16x32_bf16(av.h, bf[ks], acc[cf], 0, 0, 0);
        }
      }
#pragma unroll
      for (int cf = 0; cf < 8; cf++) {
        float4 g4 = *(const float4*)(gb + r * DD + cf * 16 + fh * 4);
        const float* gp = (const float*)&g4;
#pragma unroll
        for (int j = 0; j < 4; j++) {
          float f = acc[cf][j] + gp[j];
          sa[cf][j] += f;
          qa[cf][j] += f * f;
        }
      }
    }

    // relayout s -> sf frags (per-wave LDS)
    bf16x8 sf[4], df[4];
#pragma unroll
    for (int cf = 0; cf < 8; cf++) {
      int wb = cf * 8 + fh * 2;
      wbuf[nl * 68 + wb]     = (u32)f2bf(sa[cf][0]) | ((u32)f2bf(sa[cf][1]) << 16);
      wbuf[nl * 68 + wb + 1] = (u32)f2bf(sa[cf][2]) | ((u32)f2bf(sa[cf][3]) << 16);
    }
#pragma unroll
    for (int ks = 0; ks < 4; ks++) {
      frag_cvt cv;
      cv.u = *(const uint4*)&wbuf[nl * 68 + ks * 16 + fh * 4];
      sf[ks] = cv.h;
    }
    // relayout dfm -> df frags
#pragma unroll
    for (int cf = 0; cf < 8; cf++) {
      int wb = cf * 8 + fh * 2;
      float d0 = 0.5f * (sa[cf][0] * sa[cf][0] - qa[cf][0]);
      float d1 = 0.5f * (sa[cf][1] * sa[cf][1] - qa[cf][1]);
      float d2 = 0.5f * (sa[cf][2] * sa[cf][2] - qa[cf][2]);
      float d3 = 0.5f * (sa[cf][3] * sa[cf][3] - qa[cf][3]);
      wbuf[nl * 68 + wb]     = (u32)f2bf(d0) | ((u32)f2bf(d1) << 16);
      wbuf[nl * 68 + wb + 1] = (u32)f2bf(d2) | ((u32)f2bf(d3) << 16);
    }
#pragma unroll
    for (int ks = 0; ks < 4; ks++) {
      frag_cvt cv;
      cv.u = *(const uint4*)&wbuf[nl * 68 + ks * 16 + fh * 4];
      df[ks] = cv.h;
    }

    // combine MFMA (WB from LDS, staged once)
    f32x4 accB[8], accS[8];
#pragma unroll
    for (int cf = 0; cf < 8; cf++) {
      accB[cf] = (f32x4){0,0,0,0};
      accS[cf] = (f32x4){0,0,0,0};
    }
#pragma unroll
    for (int ks = 0; ks < 4; ks++) {
#pragma unroll
      for (int cf = 0; cf < 8; cf++) {
        frag_cvt ab, as;
        ab.u = *(const uint4*)&lwb[(((0 * 8 + cf) * 4 + ks) * 64 + lane) * 4];
        as.u = *(const uint4*)&lwb[(((1 * 8 + cf) * 4 + ks) * 64 + lane) * 4];
        accB[cf] = __builtin_amdgcn_mfma_f32_16x16x32_bf16(ab.h, df[ks], accB[cf], 0, 0, 0);
        accS[cf] = __builtin_amdgcn_mfma_f32_16x16x32_bf16(as.h, sf[ks], accS[cf], 0, 0, 0);
      }
    }

    // epilogue: vals in registers, LN stats, two-pass coalesced out via obuf
    float4 vals[8];
    float sv = 0.f, sq = 0.f;
#pragma unroll
    for (int cf = 0; cf < 8; cf++) {
      int c0 = cf * 16 + fh * 4;
      float4 bb4 = *(const float4*)(bi_b + c0);
      float4 sb4 = *(const float4*)(si_b + c0);
      float4 xv = make_float4(0.f, 0.f, 0.f, 0.f);
      if (node < N) xv = *(const float4*)(x + (size_t)node * DD + c0);
      const float* bbp = (const float*)&bb4;
      const float* sbp = (const float*)&sb4;
      const float* xvp = (const float*)&xv;
      float* vp = (float*)&vals[cf];
#pragma unroll
      for (int j = 0; j < 4; j++) {
        float val = lrelu(accB[cf][j] + bbp[j], 0.01f)
                  + lrelu(accS[cf][j] + sbp[j], 0.01f)
                  + xvp[j] * sigw;
        vp[j] = val;
        sv += val; sq += val * val;
      }
    }
    sv += __shfl_xor(sv, 16); sq += __shfl_xor(sq, 16);
    sv += __shfl_xor(sv, 32); sq += __shfl_xor(sq, 32);
    const float mu = sv * (1.f / DD);
    const float var = sq * (1.f / DD) - mu * mu;
    const float rs = rsqrtf(var + 1e-5f);

#pragma unroll
    for (int half = 0; half < 2; half++) {
      const float g = half ? gB : gA;
      const float b = half ? bB : bA;
#pragma unroll
      for (int cf = 0; cf < 4; cf++)
        *(float4*)&obuf[nl * 66 + cf * 16 + fh * 4] = vals[half * 4 + cf];
#pragma unroll
      for (int rr = 0; rr < 16; rr++) {
        int n2 = tb + rr;
        if (n2 >= N) continue;
        float mur = __shfl(mu, rr);
        float rsr = __shfl(rs, rr);
        float v = obuf[rr * 66 + lane];
        out[(size_t)n2 * DD + half * 64 + lane] = (v - mur) * rsr * g + b;
      }
    }
  }
}

extern "C" void kernel_launch(void* const* d_in, const int* in_sizes, int n_in,
                              void* d_out, int out_size, void* d_ws, size_t ws_size,
                              hipStream_t stream)
{
  const float* x    = (const float*)d_in[0];
  const int*   esrc = (const int*)d_in[1];
  const int*   edst = (const int*)d_in[2];
  const float* ew   = (const float*)d_in[3];
  const float* W    = (const float*)d_in[4];
  const float* al   = (const float*)d_in[5];
  const float* ar   = (const float*)d_in[6];
  const float* gb   = (const float*)d_in[7];
  const float* bi_w = (const float*)d_in[8];
  const float* bi_b = (const float*)d_in[9];
  const float* si_w = (const float*)d_in[10];
  const float* si_b = (const float*)d_in[11];
  const float* res_w= (const float*)d_in[12];
  const float* ln_g = (const float*)d_in[13];
  const float* ln_b = (const float*)d_in[14];

  const int N = in_sizes[0] / DD;
  const int R = 3;
  const int E = in_sizes[1] / R;
  const int Np = ((N + 127) / 128) * 128;
  const int M = R * N;
  const int NB = (M + 2047) / 2048;
  const int ntiles = Np / 128;

  auto al256 = [](size_t v) { return (v + 255) & ~(size_t)255; };
  char* p = (char*)d_ws;
  u32*   xrow  = (u32*)p;  p += al256((size_t)Np * 64 * 4);
  // region C: rank [hist..scatter]  then  aggx [node_agg..tail2]
  int*   rank  = (int*)p;
  u32*   aggx  = (u32*)p;
  p += al256((size_t)R * Np * 64 * 4);
  int2*  meta  = (int2*)p;  p += al256((size_t)R * E * 8);
  float* el    = (float*)p; p += al256((size_t)M * 4);
  int2*  bex   = (int2*)p;  p += al256(((size_t)M + 1) * 8);
  int*   cnt   = (int*)p;   p += al256((size_t)M * 4);
  short* WA    = (short*)p; p += al256((size_t)R * 8 * 4 * 64 * 8 * 2);
  short* WB    = (short*)p; p += al256((size_t)2 * 8 * 4 * 64 * 8 * 2);
  float* wl    = (float*)p; p += al256((size_t)R * DD * 4);
  float* wr    = (float*)p; p += al256((size_t)R * DD * 4);
  int*   bsum  = (int*)p;   p += 1024;
  int*   bpre  = (int*)p;   p += 1024;

  const int egrid = (E + 255) / 256;
  const int DYN_LDS = 133120;  // 130 KB

  hipFuncSetAttribute((const void*)k_tail2,
                      hipFuncAttributeMaxDynamicSharedMemorySize, DYN_LDS);

  k_prep_w<<<24, 256, 0, stream>>>(W, WA);
  k_prep_cw<<<16, 256, 0, stream>>>(bi_w, si_w, WB);
  k_prep_av<<<2, 192, 0, stream>>>(W, al, ar, wl, wr);
  k_prep_xrow<<<(N + 3) / 4, 256, 0, stream>>>(x, wl, wr, xrow, el, bex, N);

  hipMemsetAsync(cnt, 0, (size_t)M * 4, stream);
  k_hist3<<<dim3(egrid, 3), 256, 0, stream>>>(edst, cnt, rank, N, E);
  k_scan_bsum<<<NB, 256, 0, stream>>>(cnt, bsum, M);
  k_scan_btop<<<1, 256, 0, stream>>>(bsum, bpre, NB);
  k_scan_base<<<NB, 256, 0, stream>>>(cnt, bpre, bex, M);
  k_scatter3<<<dim3(egrid, 3), 256, 0, stream>>>(esrc, edst, ew, el, rank, bex,
                                                 meta, N, E);
  k_node_agg3<<<(N + 3) / 4, 256, 0, stream>>>(bex, meta, xrow, aggx, N, Np);
  k_tail2<<<256, 512, DYN_LDS, stream>>>(aggx, WA, WB, gb, x, bi_b, si_b,
                                         res_w, ln_g, ln_b, (float*)d_out,
                                         N, Np, ntiles);
}